// Round 18
// baseline (187.618 us; speedup 1.0000x reference)
//
#include <hip/hip_runtime.h>
#include <math.h>

using bf16x8  = __attribute__((ext_vector_type(8))) __bf16;
using floatx4 = __attribute__((ext_vector_type(4))) float;
using ushortx8 = __attribute__((ext_vector_type(8))) unsigned short;
using ushortx4 = __attribute__((ext_vector_type(4))) unsigned short;
typedef unsigned short u16;

__device__ __forceinline__ float bf2f(u16 u) {
  unsigned int x = ((unsigned int)u) << 16;
  return __builtin_bit_cast(float, x);
}
__device__ __forceinline__ u16 f2bf(float f) {
  unsigned int x = __builtin_bit_cast(unsigned int, f);
  x += 0x7FFFu + ((x >> 16) & 1u);   // round-to-nearest-even
  return (u16)(x >> 16);
}
__device__ __forceinline__ float fexp2(float x) { return __builtin_amdgcn_exp2f(x); }
__device__ __forceinline__ unsigned cvtpk(float lo, float hi) {
  unsigned r;
  asm("v_cvt_pk_bf16_f32 %0, %1, %2" : "=v"(r) : "v"(lo), "v"(hi));
  return r;
}
// uniform scale reduction from absum partials (same order as old scales_kernel)
__device__ __forceinline__ float scale_of(const float* __restrict__ partials, int w) {
  float s = 0.f;
  for (int i = 0; i < 64; ++i) s += partials[w * 64 + i];
  return s * (1.f / 1048576.f);
}

#define GLDS16(SRC, DST)                                                        \
  __builtin_amdgcn_global_load_lds((const __attribute__((address_space(1))) void*)(SRC), \
                                   (__attribute__((address_space(3))) void*)(DST), 16, 0, 0)

// ---------------- prep: x fp32->bf16 (blocks 0..2047) + weight |W| partials (blocks 2048..2303) ----------------
__global__ __launch_bounds__(256) void prep_kernel(const float* __restrict__ x, u16* __restrict__ xb,
                                                   const float* W0, const float* W1,
                                                   const float* W2, const float* W3,
                                                   float* partials) {
  __shared__ float red[256];
  int tid = threadIdx.x;
  if (blockIdx.x < 2048) {
    int g = (blockIdx.x * 256 + tid) * 8;
    float4 a = *(const float4*)(x + g);
    float4 b = *(const float4*)(x + g + 4);
    ushortx8 o;
    o[0] = f2bf(a.x); o[1] = f2bf(a.y); o[2] = f2bf(a.z); o[3] = f2bf(a.w);
    o[4] = f2bf(b.x); o[5] = f2bf(b.y); o[6] = f2bf(b.z); o[7] = f2bf(b.w);
    *(ushortx8*)(xb + g) = o;
    return;
  }
  int idx = blockIdx.x - 2048;              // 0..255
  int bx = idx & 63, w = idx >> 6;
  const float* W = (w == 0) ? W0 : (w == 1) ? W1 : (w == 2) ? W2 : W3;
  int base = bx * 16384 + tid;
  float s = 0.f;
#pragma unroll
  for (int i = 0; i < 64; ++i) s += fabsf(W[base + i * 256]);
  red[tid] = s;
  __syncthreads();
  for (int off = 128; off > 0; off >>= 1) {
    if (tid < off) red[tid] += red[tid + off];
    __syncthreads();
  }
  if (tid == 0) partials[w * 64 + bx] = red[0];
}

// ---------------- ternary quantize (vectorized x4, inline scale) ----------------
__global__ __launch_bounds__(256) void quant_kernel(const float* W0, const float* W1,
                                                    const float* W2, const float* W3,
                                                    const float* partials, u16* Wt) {
  int w = blockIdx.y;
  const float* W = (w == 0) ? W0 : (w == 1) ? W1 : (w == 2) ? W2 : W3;
  u16* O = Wt + (size_t)w * (1u << 20);
  float s = scale_of(partials, w) + 1e-8f;
  int e = (blockIdx.x * 256 + threadIdx.x) * 4;
  float4 v = *(const float4*)(W + e);
  ushortx4 o;
  o[0] = f2bf(rintf(fminf(fmaxf(v.x / s, -1.f), 1.f)));
  o[1] = f2bf(rintf(fminf(fmaxf(v.y / s, -1.f), 1.f)));
  o[2] = f2bf(rintf(fminf(fmaxf(v.z / s, -1.f), 1.f)));
  o[3] = f2bf(rintf(fminf(fmaxf(v.w / s, -1.f), 1.f)));
  *(ushortx4*)(O + e) = o;
}

// ---------------- fused QKV GEMM: 128x64 tile, BK=64, depth-2 counted-vmcnt pipeline ----------------
// T4 done right (R16's miss): raw s_barrier + s_waitcnt vmcnt(6) keeps the NEWEST stage's
// 6 glds in flight across the barrier, draining only the previous tile's loads. Per iter:
// vmcnt(6) -> barrier -> 32 MFMA on buf b -> barrier -> restage buf b with tile i+2.
// All ds_reads of b are consumed by MFMAs before the 2nd barrier (compiler lgkmcnt), so
// re-staging is hazard-free. Last iter uses vmcnt(0). Chunk-XOR swizzle throughout.
// Epilogue: mat 0/1 -> fused RoPE (+QS fold into Q); mat 2 -> fused V transpose.
__global__ __launch_bounds__(256) void gemm_qkv(const u16* __restrict__ A, const u16* __restrict__ Wt,
                                                u16* __restrict__ QKV, u16* __restrict__ vt,
                                                const float* __restrict__ partials) {
  const int K = 1024;
  __shared__ __align__(16) u16 As[2][128][64];
  __shared__ __align__(16) u16 Bs[2][64][64];
  int tid = threadIdx.x;
  int wave = tid >> 6, lane = tid & 63;
  int quad = lane >> 4, l16 = lane & 15;
  int bm = blockIdx.x * 128;
  int bnc = blockIdx.y * 64;               // 64-col tile never spans matrices
  int mat = bnc >> 10, bn = bnc & 1023;
  int wm = wave * 32;
  floatx4 acc[2][4] = {};
  // staging: glds lane l covers row offset (l>>3), slot chunk (l&7); pre-swizzle global col
  int scol = ((lane & 7) ^ ((lane >> 3) & 7)) * 8;
  const u16* ga = A  + (size_t)(bm + wave * 32 + (lane >> 3)) * K + scol;
  const u16* gb = Wt + (size_t)(bnc + wave * 16 + (lane >> 3)) * K + scol;
  int rx = (l16 & 7);                      // row&7 for frag reads

#define STAGE_AB(BB, KO)                                                        \
  do {                                                                          \
    _Pragma("unroll")                                                           \
    for (int i_ = 0; i_ < 4; ++i_)                                              \
      GLDS16(ga + (size_t)i_ * 8 * K + (KO), &As[BB][wave * 32 + i_ * 8][0]);   \
    _Pragma("unroll")                                                           \
    for (int i_ = 0; i_ < 2; ++i_)                                              \
      GLDS16(gb + (size_t)i_ * 8 * K + (KO), &Bs[BB][wave * 16 + i_ * 8][0]);   \
  } while (0)

  STAGE_AB(0, 0);
  STAGE_AB(1, 64);
  for (int k0 = 0; k0 < K; k0 += 64) {
    int bb = (k0 >> 6) & 1;
    // drain ONLY the previous stage's 6 loads (each wave issues 6/stage); newest stays in flight
    if (k0 == K - 64) asm volatile("s_waitcnt vmcnt(0)" ::: "memory");
    else              asm volatile("s_waitcnt vmcnt(6)" ::: "memory");
    __builtin_amdgcn_sched_barrier(0);
    __builtin_amdgcn_s_barrier();
    __builtin_amdgcn_sched_barrier(0);
#pragma unroll
    for (int kk = 0; kk < 64; kk += 32) {
      int col = (((kk >> 3) + quad) ^ rx) * 8;   // swizzled chunk of logical (kk/8 + quad)
      bf16x8 a[2], b[4];
#pragma unroll
      for (int i = 0; i < 2; ++i)
        a[i] = __builtin_bit_cast(bf16x8, *(const ushortx8*)&As[bb][wm + i * 16 + l16][col]);
#pragma unroll
      for (int j = 0; j < 4; ++j)
        b[j] = __builtin_bit_cast(bf16x8, *(const ushortx8*)&Bs[bb][j * 16 + l16][col]);
#pragma unroll
      for (int i = 0; i < 2; ++i)
#pragma unroll
        for (int j = 0; j < 4; ++j)
          acc[i][j] = __builtin_amdgcn_mfma_f32_16x16x32_bf16(a[i], b[j], acc[i][j], 0, 0, 0);
    }
    __builtin_amdgcn_s_barrier();          // all waves done reading buf bb (reads consumed by MFMAs)
    __builtin_amdgcn_sched_barrier(0);
    if (k0 + 128 < K) STAGE_AB(bb, k0 + 128);
  }
#undef STAGE_AB

  float sc = scale_of(partials, mat);
  if (mat < 2) {
    // fused RoPE: d = j*16 + l16 (j in {0,1}) pairs with d+32 (acc j+2); QS folded into Q
    u16* outp = QKV + (size_t)mat * (4u << 20);
    float qs = (mat == 0) ? 0.125f * 1.4426950408889634f : 1.0f;
    float inv0 = exp2f(-(float)l16 * (13.287712379549449f / 32.f));
    float inv1 = exp2f(-(float)(16 + l16) * (13.287712379549449f / 32.f));
#pragma unroll
    for (int i = 0; i < 2; ++i)
#pragma unroll
      for (int rg = 0; rg < 4; ++rg) {
        int row = bm + wm + i * 16 + quad * 4 + rg;
        float tf = (float)(row & 2047);
#pragma unroll
        for (int j = 0; j < 2; ++j) {
          float ang = tf * (j ? inv1 : inv0);
          float s = __sinf(ang), c = __cosf(ang);
          float v1 = acc[i][j][rg] * sc, v2 = acc[i][j + 2][rg] * sc;
          int col = bn + j * 16 + l16;
          outp[(size_t)row * 1024 + col]      = f2bf((v1 * c - v2 * s) * qs);
          outp[(size_t)row * 1024 + col + 32] = f2bf((v2 * c + v1 * s) * qs);
        }
      }
  } else {
    // fused V transpose: vt[(b*16+h)*64 + d][t], packed 4-token (8B) stores
    int h = bn >> 6;
#pragma unroll
    for (int i = 0; i < 2; ++i) {
      int row0 = bm + wm + i * 16 + quad * 4;
      int b = row0 >> 11, t0 = row0 & 2047;
#pragma unroll
      for (int j = 0; j < 4; ++j) {
        int d = j * 16 + l16;
        ushortx4 o;
#pragma unroll
        for (int rg = 0; rg < 4; ++rg) o[rg] = f2bf(acc[i][j][rg] * sc);
        *(ushortx4*)(vt + (size_t)((b * 16 + h) * 64 + d) * 2048 + t0) = o;
      }
    }
  }
}

// ---------------- output projection GEMM (fp32 out): 128x64 tile + chunk-XOR swizzle ----------------
__global__ __launch_bounds__(256) void gemm_out(const u16* __restrict__ A, const u16* __restrict__ B,
                                                float* __restrict__ C, const float* __restrict__ partials) {
  const int K = 1024, N = 1024;
  __shared__ __align__(16) u16 As[128][64];
  __shared__ __align__(16) u16 Bs[64][64];
  int tid = threadIdx.x;
  int wave = tid >> 6, lane = tid & 63;
  int quad = lane >> 4, l16 = lane & 15;
  int bm = blockIdx.x * 128, bn = blockIdx.y * 64;
  int wm = (wave >> 1) * 64, wn = (wave & 1) * 32;
  floatx4 acc[4][2] = {};
  int scol = ((lane & 7) ^ ((lane >> 3) & 7)) * 8;
  const u16* ga = A + (size_t)(bm + wave * 32 + (lane >> 3)) * K + scol;
  const u16* gb = B + (size_t)(bn + wave * 16 + (lane >> 3)) * K + scol;
  int rx = (l16 & 7);
  for (int k0 = 0; k0 < K; k0 += 64) {
    __syncthreads();
#pragma unroll
    for (int i = 0; i < 4; ++i)
      GLDS16(ga + (size_t)i * 8 * K + k0, &As[wave * 32 + i * 8][0]);
#pragma unroll
    for (int i = 0; i < 2; ++i)
      GLDS16(gb + (size_t)i * 8 * K + k0, &Bs[wave * 16 + i * 8][0]);
    __syncthreads();
#pragma unroll
    for (int kk = 0; kk < 64; kk += 32) {
      int col = (((kk >> 3) + quad) ^ rx) * 8;
      bf16x8 a[4], b[2];
#pragma unroll
      for (int i = 0; i < 4; ++i)
        a[i] = __builtin_bit_cast(bf16x8, *(const ushortx8*)&As[wm + i * 16 + l16][col]);
#pragma unroll
      for (int j = 0; j < 2; ++j)
        b[j] = __builtin_bit_cast(bf16x8, *(const ushortx8*)&Bs[wn + j * 16 + l16][col]);
#pragma unroll
      for (int i = 0; i < 4; ++i)
#pragma unroll
        for (int j = 0; j < 2; ++j)
          acc[i][j] = __builtin_amdgcn_mfma_f32_16x16x32_bf16(a[i], b[j], acc[i][j], 0, 0, 0);
    }
  }
  float sc = scale_of(partials, 3);
#pragma unroll
  for (int i = 0; i < 4; ++i)
#pragma unroll
    for (int j = 0; j < 2; ++j)
#pragma unroll
      for (int rg = 0; rg < 4; ++rg) {
        int row = bm + wm + i * 16 + quad * 4 + rg;
        int col = bn + wn + j * 16 + l16;
        C[(size_t)row * N + col] = acc[i][j][rg] * sc;
      }
}

// ---------------- causal flash attention: balanced strip pairs, fixed-zero softmax max ----------------
// Grid (bh=32, p=16): per-XCD K/V L2 reuse (R13: FETCH 62.5 -> 12.3 MB). K/V staged via
// global_load_lds into [64][64] tiles with chunk-XOR swizzle (stored chunk = logical ^
// (row&7), pre-swizzled global source) -> no VGPR roundtrip, no ds_write phase; drain
// folds into the tile-end barrier's vmcnt(0). rcp epilogue.
__global__ __launch_bounds__(256, 3) void attn_kernel(const u16* __restrict__ q, const u16* __restrict__ k,
                                                      const u16* __restrict__ vt, u16* __restrict__ y) {
  __shared__ __align__(16) u16 Ks[2][64][64];
  __shared__ __align__(16) u16 Vt[2][64][64];
  __shared__ __align__(16) u16 Ps[4][16][72];
  const int T = 2048, C = 1024;
  int tid = threadIdx.x;
  int wave = tid >> 6, lane = tid & 63;
  int quad = lane >> 4, l16 = lane & 15;
  int p = blockIdx.y;                       // 0..15 -> strips p and 31-p
  int bh = blockIdx.x;                      // 0..31 = b*16+h (fastest-varying)
  int b = bh >> 4, h = bh & 15;
  int wq[2];
  wq[0] = p * 64 + wave * 16;               // group A
  wq[1] = (31 - p) * 64 + wave * 16;        // group B
  int dt[2] = {p, 31 - p};                  // diagonal 64-key tile per group
  int nkt = 32 - p;                         // tiles 0..31-p

  bf16x8 bq[2][2];
#pragma unroll
  for (int g = 0; g < 2; ++g) {
    const u16* gq = q + (size_t)(b * T + wq[g] + l16) * C + h * 64 + quad * 8;
    bq[g][0] = __builtin_bit_cast(bf16x8, *(const ushortx8*)(gq));
    bq[g][1] = __builtin_bit_cast(bf16x8, *(const ushortx8*)(gq + 32));
  }

  ushortx8 onesu;
#pragma unroll
  for (int j = 0; j < 8; ++j) onesu[j] = 0x3F80;  // bf16 1.0
  bf16x8 bones = __builtin_bit_cast(bf16x8, onesu);

  // glds staging: issue (w + 4i) covers rows (w+4i)*8 .. +7; lane covers row +(lane>>3),
  // stored chunk (lane&7); global source column pre-swizzled by row&7 = lane>>3.
  int grow = lane >> 3;                     // row offset within 8-row group
  int gchk = ((lane & 7) ^ grow) * 8;       // pre-swizzled logical chunk
  const u16* kbase = k  + (size_t)(b * T + grow) * C + h * 64 + gchk;
  const u16* vbase = vt + (size_t)(bh * 64 + grow) * 2048 + gchk;

#define STAGE_KV(BB, KT)                                                                     \
  do {                                                                                       \
    _Pragma("unroll")                                                                        \
    for (int i_ = 0; i_ < 2; ++i_) {                                                         \
      int rb_ = (wave + 4 * i_) * 8;                                                         \
      GLDS16(kbase + (size_t)((KT) * 64 + rb_) * C, &Ks[BB][rb_][0]);                        \
      GLDS16(vbase + (size_t)rb_ * 2048 + (KT) * 64, &Vt[BB][rb_][0]);                       \
    }                                                                                        \
  } while (0)

  floatx4 o[2][5] = {};  // [group][0..3]=O tiles, [4]=row-sum l

  STAGE_KV(0, 0);
  __syncthreads();

  int rxk = l16 & 7;                        // row&7 for K/V frag reads

  for (int kt = 0; kt < nkt; ++kt) {
    int cur = kt & 1;
    if (kt + 1 < nkt) STAGE_KV(cur ^ 1, kt + 1);   // nb freed by the barrier ending kt-1

    bool act[2] = {kt <= dt[0], true};

    // S^T = K Q^T : lane holds S[q=l16][key = kt*64 + nt*16 + quad*4 + rg]
    floatx4 sacc[2][4] = {};
#pragma unroll
    for (int nt = 0; nt < 4; ++nt) {
      bf16x8 ak0 = __builtin_bit_cast(bf16x8, *(const ushortx8*)&Ks[cur][nt * 16 + l16][(quad ^ rxk) * 8]);
      bf16x8 ak1 = __builtin_bit_cast(bf16x8, *(const ushortx8*)&Ks[cur][nt * 16 + l16][((quad | 4) ^ rxk) * 8]);
#pragma unroll
      for (int g = 0; g < 2; ++g)
        if (act[g]) {
          sacc[g][nt] = __builtin_amdgcn_mfma_f32_16x16x32_bf16(ak0, bq[g][0], sacc[g][nt], 0, 0, 0);
          sacc[g][nt] = __builtin_amdgcn_mfma_f32_16x16x32_bf16(ak1, bq[g][1], sacc[g][nt], 0, 0, 0);
        }
    }

    // per group: mask+softmax, write shared Ps slot, read A-frag back (same-wave in-order DS)
    bf16x8 ap[2][2];
#pragma unroll
    for (int g = 0; g < 2; ++g)
      if (act[g]) {
        if (kt == dt[g]) {  // causal mask, this group's diagonal tile
          int qg = wq[g] + l16;
#pragma unroll
          for (int nt = 0; nt < 4; ++nt)
#pragma unroll
            for (int rg = 0; rg < 4; ++rg)
              if (kt * 64 + nt * 16 + quad * 4 + rg > qg) sacc[g][nt][rg] = -__builtin_inff();
        }
        // fixed m = 0: P = exp2(S), no running max / no rescale
#pragma unroll
        for (int nt = 0; nt < 4; ++nt) {
          float p0 = fexp2(sacc[g][nt][0]);
          float p1 = fexp2(sacc[g][nt][1]);
          float p2 = fexp2(sacc[g][nt][2]);
          float p3 = fexp2(sacc[g][nt][3]);
          unsigned lo = cvtpk(p0, p1);
          unsigned hi = cvtpk(p2, p3);
          *(uint2*)&Ps[wave][l16][nt * 16 + quad * 4] = make_uint2(lo, hi);
        }
        ap[g][0] = __builtin_bit_cast(bf16x8, *(const ushortx8*)&Ps[wave][l16][quad * 8]);
        ap[g][1] = __builtin_bit_cast(bf16x8, *(const ushortx8*)&Ps[wave][l16][32 + quad * 8]);
      }

#pragma unroll
    for (int nt = 0; nt < 4; ++nt) {
      bf16x8 bv0 = __builtin_bit_cast(bf16x8, *(const ushortx8*)&Vt[cur][nt * 16 + l16][(quad ^ rxk) * 8]);
      bf16x8 bv1 = __builtin_bit_cast(bf16x8, *(const ushortx8*)&Vt[cur][nt * 16 + l16][((quad | 4) ^ rxk) * 8]);
#pragma unroll
      for (int g = 0; g < 2; ++g)
        if (act[g]) {
          o[g][nt] = __builtin_amdgcn_mfma_f32_16x16x32_bf16(ap[g][0], bv0, o[g][nt], 0, 0, 0);
          o[g][nt] = __builtin_amdgcn_mfma_f32_16x16x32_bf16(ap[g][1], bv1, o[g][nt], 0, 0, 0);
        }
    }
#pragma unroll
    for (int g = 0; g < 2; ++g)
      if (act[g]) {
        o[g][4] = __builtin_amdgcn_mfma_f32_16x16x32_bf16(ap[g][0], bones, o[g][4], 0, 0, 0);
        o[g][4] = __builtin_amdgcn_mfma_f32_16x16x32_bf16(ap[g][1], bones, o[g][4], 0, 0, 0);
      }

    __syncthreads();  // single barrier per tile; drains glds (vmcnt) + LDS reads
  }
#undef STAGE_KV

#pragma unroll
  for (int g = 0; g < 2; ++g) {
    float inv[4];
#pragma unroll
    for (int rg = 0; rg < 4; ++rg) inv[rg] = __builtin_amdgcn_rcpf(o[g][4][rg]);
#pragma unroll
    for (int nt = 0; nt < 4; ++nt)
#pragma unroll
      for (int rg = 0; rg < 4; ++rg) {
        int qg = wq[g] + quad * 4 + rg;
        int col = h * 64 + nt * 16 + l16;
        y[(size_t)(b * T + qg) * C + col] = f2bf(o[g][nt][rg] * inv[rg]);
      }
  }
}

extern "C" void kernel_launch(void* const* d_in, const int* in_sizes, int n_in,
                              void* d_out, int out_size, void* d_ws, size_t ws_size,
                              hipStream_t stream) {
  const float* x  = (const float*)d_in[0];
  const float* Wq = (const float*)d_in[1];
  const float* Wk = (const float*)d_in[2];
  const float* Wv = (const float*)d_in[3];
  const float* Wo = (const float*)d_in[4];

  char* ws = (char*)d_ws;
  float* partials = (float*)ws;
  u16* Wt  = (u16*)(ws + 4096);                       // 4 x 1M bf16 ternary (Q,K,V,O stacked)
  u16* xb  = (u16*)(ws + 4096 + (size_t)(8u << 20));
  u16* qb  = xb + (4u << 20);                         // qb,kb contiguous (QKV epilogue routing)
  u16* kb  = qb + (4u << 20);
  u16* vtb = kb + (4u << 20);                         // V written directly transposed
  u16* yb  = vtb + (4u << 20);
  float* out = (float*)d_out;

  prep_kernel<<<2304, 256, 0, stream>>>(x, xb, Wq, Wk, Wv, Wo, partials);
  quant_kernel<<<dim3(1024, 4), 256, 0, stream>>>(Wq, Wk, Wv, Wo, partials, Wt);

  gemm_qkv<<<dim3(32, 48), 256, 0, stream>>>(xb, Wt, qb, vtb, partials);  // RoPE + V-transpose fused
  attn_kernel<<<dim3(32, 16), 256, 0, stream>>>(qb, kb, vtb, yb);         // bh fastest -> per-XCD K/V L2 reuse
  gemm_out<<<dim3(32, 16), 256, 0, stream>>>(yb, Wt + 3 * (1u << 20), out, partials);
}

// Round 19
// 182.675 us; speedup vs baseline: 1.0271x; 1.0271x over previous
//
#include <hip/hip_runtime.h>
#include <math.h>

using bf16x8  = __attribute__((ext_vector_type(8))) __bf16;
using floatx4 = __attribute__((ext_vector_type(4))) float;
using ushortx8 = __attribute__((ext_vector_type(8))) unsigned short;
using ushortx4 = __attribute__((ext_vector_type(4))) unsigned short;
typedef unsigned short u16;

__device__ __forceinline__ float bf2f(u16 u) {
  unsigned int x = ((unsigned int)u) << 16;
  return __builtin_bit_cast(float, x);
}
__device__ __forceinline__ u16 f2bf(float f) {
  unsigned int x = __builtin_bit_cast(unsigned int, f);
  x += 0x7FFFu + ((x >> 16) & 1u);   // round-to-nearest-even
  return (u16)(x >> 16);
}
__device__ __forceinline__ float fexp2(float x) { return __builtin_amdgcn_exp2f(x); }
__device__ __forceinline__ unsigned cvtpk(float lo, float hi) {
  unsigned r;
  asm("v_cvt_pk_bf16_f32 %0, %1, %2" : "=v"(r) : "v"(lo), "v"(hi));
  return r;
}
// uniform scale reduction from absum partials (same order as old scales_kernel)
__device__ __forceinline__ float scale_of(const float* __restrict__ partials, int w) {
  float s = 0.f;
  for (int i = 0; i < 64; ++i) s += partials[w * 64 + i];
  return s * (1.f / 1048576.f);
}

#define GLDS16(SRC, DST)                                                        \
  __builtin_amdgcn_global_load_lds((const __attribute__((address_space(1))) void*)(SRC), \
                                   (__attribute__((address_space(3))) void*)(DST), 16, 0, 0)

// ---------------- prep: x fp32->bf16 (blocks 0..2047) + weight |W| partials (blocks 2048..2303) ----------------
__global__ __launch_bounds__(256) void prep_kernel(const float* __restrict__ x, u16* __restrict__ xb,
                                                   const float* W0, const float* W1,
                                                   const float* W2, const float* W3,
                                                   float* partials) {
  __shared__ float red[256];
  int tid = threadIdx.x;
  if (blockIdx.x < 2048) {
    int g = (blockIdx.x * 256 + tid) * 8;
    float4 a = *(const float4*)(x + g);
    float4 b = *(const float4*)(x + g + 4);
    ushortx8 o;
    o[0] = f2bf(a.x); o[1] = f2bf(a.y); o[2] = f2bf(a.z); o[3] = f2bf(a.w);
    o[4] = f2bf(b.x); o[5] = f2bf(b.y); o[6] = f2bf(b.z); o[7] = f2bf(b.w);
    *(ushortx8*)(xb + g) = o;
    return;
  }
  int idx = blockIdx.x - 2048;              // 0..255
  int bx = idx & 63, w = idx >> 6;
  const float* W = (w == 0) ? W0 : (w == 1) ? W1 : (w == 2) ? W2 : W3;
  int base = bx * 16384 + tid;
  float s = 0.f;
#pragma unroll
  for (int i = 0; i < 64; ++i) s += fabsf(W[base + i * 256]);
  red[tid] = s;
  __syncthreads();
  for (int off = 128; off > 0; off >>= 1) {
    if (tid < off) red[tid] += red[tid + off];
    __syncthreads();
  }
  if (tid == 0) partials[w * 64 + bx] = red[0];
}

// ---------------- ternary quantize (vectorized x8, inline scale) ----------------
__global__ __launch_bounds__(256) void quant_kernel(const float* W0, const float* W1,
                                                    const float* W2, const float* W3,
                                                    const float* partials, u16* Wt) {
  int w = blockIdx.y;
  const float* W = (w == 0) ? W0 : (w == 1) ? W1 : (w == 2) ? W2 : W3;
  u16* O = Wt + (size_t)w * (1u << 20);
  float s = scale_of(partials, w) + 1e-8f;
  int e = (blockIdx.x * 256 + threadIdx.x) * 8;
  float4 v0 = *(const float4*)(W + e);
  float4 v1 = *(const float4*)(W + e + 4);
  ushortx8 o;
  o[0] = f2bf(rintf(fminf(fmaxf(v0.x / s, -1.f), 1.f)));
  o[1] = f2bf(rintf(fminf(fmaxf(v0.y / s, -1.f), 1.f)));
  o[2] = f2bf(rintf(fminf(fmaxf(v0.z / s, -1.f), 1.f)));
  o[3] = f2bf(rintf(fminf(fmaxf(v0.w / s, -1.f), 1.f)));
  o[4] = f2bf(rintf(fminf(fmaxf(v1.x / s, -1.f), 1.f)));
  o[5] = f2bf(rintf(fminf(fmaxf(v1.y / s, -1.f), 1.f)));
  o[6] = f2bf(rintf(fminf(fmaxf(v1.z / s, -1.f), 1.f)));
  o[7] = f2bf(rintf(fminf(fmaxf(v1.w / s, -1.f), 1.f)));
  *(ushortx8*)(O + e) = o;
}

// ---------------- fused QKV GEMM: 128x64 tile, BK=64, 2-barrier + chunk-XOR LDS swizzle ----------------
// Best-measured structure (R15/R17). Epilogue: mat 0/1 -> fused RoPE (+QS fold into Q);
// mat 2 -> fused V transpose.
__global__ __launch_bounds__(256) void gemm_qkv(const u16* __restrict__ A, const u16* __restrict__ Wt,
                                                u16* __restrict__ QKV, u16* __restrict__ vt,
                                                const float* __restrict__ partials) {
  const int K = 1024;
  __shared__ __align__(16) u16 As[128][64];
  __shared__ __align__(16) u16 Bs[64][64];
  int tid = threadIdx.x;
  int wave = tid >> 6, lane = tid & 63;
  int quad = lane >> 4, l16 = lane & 15;
  int bm = blockIdx.x * 128;
  int bnc = blockIdx.y * 64;               // 64-col tile never spans matrices
  int mat = bnc >> 10, bn = bnc & 1023;
  int wm = wave * 32;
  floatx4 acc[2][4] = {};
  // staging: glds lane l covers row offset (l>>3), slot chunk (l&7); pre-swizzle global col
  int scol = ((lane & 7) ^ ((lane >> 3) & 7)) * 8;
  const u16* ga = A  + (size_t)(bm + wave * 32 + (lane >> 3)) * K + scol;
  const u16* gb = Wt + (size_t)(bnc + wave * 16 + (lane >> 3)) * K + scol;
  int rx = (l16 & 7);                      // row&7 for frag reads
  for (int k0 = 0; k0 < K; k0 += 64) {
    __syncthreads();
#pragma unroll
    for (int i = 0; i < 4; ++i)
      GLDS16(ga + (size_t)i * 8 * K + k0, &As[wave * 32 + i * 8][0]);
#pragma unroll
    for (int i = 0; i < 2; ++i)
      GLDS16(gb + (size_t)i * 8 * K + k0, &Bs[wave * 16 + i * 8][0]);
    __syncthreads();
#pragma unroll
    for (int kk = 0; kk < 64; kk += 32) {
      int col = (((kk >> 3) + quad) ^ rx) * 8;   // swizzled chunk of logical (kk/8 + quad)
      bf16x8 a[2], b[4];
#pragma unroll
      for (int i = 0; i < 2; ++i)
        a[i] = __builtin_bit_cast(bf16x8, *(const ushortx8*)&As[wm + i * 16 + l16][col]);
#pragma unroll
      for (int j = 0; j < 4; ++j)
        b[j] = __builtin_bit_cast(bf16x8, *(const ushortx8*)&Bs[j * 16 + l16][col]);
#pragma unroll
      for (int i = 0; i < 2; ++i)
#pragma unroll
        for (int j = 0; j < 4; ++j)
          acc[i][j] = __builtin_amdgcn_mfma_f32_16x16x32_bf16(a[i], b[j], acc[i][j], 0, 0, 0);
    }
  }
  float sc = scale_of(partials, mat);
  if (mat < 2) {
    // fused RoPE: d = j*16 + l16 (j in {0,1}) pairs with d+32 (acc j+2); QS folded into Q
    u16* outp = QKV + (size_t)mat * (4u << 20);
    float qs = (mat == 0) ? 0.125f * 1.4426950408889634f : 1.0f;
    float inv0 = exp2f(-(float)l16 * (13.287712379549449f / 32.f));
    float inv1 = exp2f(-(float)(16 + l16) * (13.287712379549449f / 32.f));
#pragma unroll
    for (int i = 0; i < 2; ++i)
#pragma unroll
      for (int rg = 0; rg < 4; ++rg) {
        int row = bm + wm + i * 16 + quad * 4 + rg;
        float tf = (float)(row & 2047);
#pragma unroll
        for (int j = 0; j < 2; ++j) {
          float ang = tf * (j ? inv1 : inv0);
          float s = __sinf(ang), c = __cosf(ang);
          float v1 = acc[i][j][rg] * sc, v2 = acc[i][j + 2][rg] * sc;
          int col = bn + j * 16 + l16;
          outp[(size_t)row * 1024 + col]      = f2bf((v1 * c - v2 * s) * qs);
          outp[(size_t)row * 1024 + col + 32] = f2bf((v2 * c + v1 * s) * qs);
        }
      }
  } else {
    // fused V transpose: vt[(b*16+h)*64 + d][t], packed 4-token (8B) stores
    int h = bn >> 6;
#pragma unroll
    for (int i = 0; i < 2; ++i) {
      int row0 = bm + wm + i * 16 + quad * 4;
      int b = row0 >> 11, t0 = row0 & 2047;
#pragma unroll
      for (int j = 0; j < 4; ++j) {
        int d = j * 16 + l16;
        ushortx4 o;
#pragma unroll
        for (int rg = 0; rg < 4; ++rg) o[rg] = f2bf(acc[i][j][rg] * sc);
        *(ushortx4*)(vt + (size_t)((b * 16 + h) * 64 + d) * 2048 + t0) = o;
      }
    }
  }
}

// ---------------- output projection GEMM (fp32 out): 128x64 tile + chunk-XOR swizzle ----------------
__global__ __launch_bounds__(256) void gemm_out(const u16* __restrict__ A, const u16* __restrict__ B,
                                                float* __restrict__ C, const float* __restrict__ partials) {
  const int K = 1024, N = 1024;
  __shared__ __align__(16) u16 As[128][64];
  __shared__ __align__(16) u16 Bs[64][64];
  int tid = threadIdx.x;
  int wave = tid >> 6, lane = tid & 63;
  int quad = lane >> 4, l16 = lane & 15;
  int bm = blockIdx.x * 128, bn = blockIdx.y * 64;
  int wm = (wave >> 1) * 64, wn = (wave & 1) * 32;
  floatx4 acc[4][2] = {};
  int scol = ((lane & 7) ^ ((lane >> 3) & 7)) * 8;
  const u16* ga = A + (size_t)(bm + wave * 32 + (lane >> 3)) * K + scol;
  const u16* gb = B + (size_t)(bn + wave * 16 + (lane >> 3)) * K + scol;
  int rx = (l16 & 7);
  for (int k0 = 0; k0 < K; k0 += 64) {
    __syncthreads();
#pragma unroll
    for (int i = 0; i < 4; ++i)
      GLDS16(ga + (size_t)i * 8 * K + k0, &As[wave * 32 + i * 8][0]);
#pragma unroll
    for (int i = 0; i < 2; ++i)
      GLDS16(gb + (size_t)i * 8 * K + k0, &Bs[wave * 16 + i * 8][0]);
    __syncthreads();
#pragma unroll
    for (int kk = 0; kk < 64; kk += 32) {
      int col = (((kk >> 3) + quad) ^ rx) * 8;
      bf16x8 a[4], b[2];
#pragma unroll
      for (int i = 0; i < 4; ++i)
        a[i] = __builtin_bit_cast(bf16x8, *(const ushortx8*)&As[wm + i * 16 + l16][col]);
#pragma unroll
      for (int j = 0; j < 2; ++j)
        b[j] = __builtin_bit_cast(bf16x8, *(const ushortx8*)&Bs[wn + j * 16 + l16][col]);
#pragma unroll
      for (int i = 0; i < 4; ++i)
#pragma unroll
        for (int j = 0; j < 2; ++j)
          acc[i][j] = __builtin_amdgcn_mfma_f32_16x16x32_bf16(a[i], b[j], acc[i][j], 0, 0, 0);
    }
  }
  float sc = scale_of(partials, 3);
#pragma unroll
  for (int i = 0; i < 4; ++i)
#pragma unroll
    for (int j = 0; j < 2; ++j)
#pragma unroll
      for (int rg = 0; rg < 4; ++rg) {
        int row = bm + wm + i * 16 + quad * 4 + rg;
        int col = bn + wn + j * 16 + l16;
        C[(size_t)row * N + col] = acc[i][j][rg] * sc;
      }
}

// ---------------- causal flash attention: balanced strip pairs, fixed-zero softmax max ----------------
// Grid (bh=32, p=16): per-XCD K/V L2 reuse (R13: FETCH 62.5 -> 12.3 MB). K/V staged via
// global_load_lds into [64][64] tiles with chunk-XOR swizzle (stored chunk = logical ^
// (row&7), pre-swizzled global source) -> no VGPR roundtrip, no ds_write phase; drain
// folds into the tile-end barrier's vmcnt(0). rcp epilogue.
__global__ __launch_bounds__(256, 3) void attn_kernel(const u16* __restrict__ q, const u16* __restrict__ k,
                                                      const u16* __restrict__ vt, u16* __restrict__ y) {
  __shared__ __align__(16) u16 Ks[2][64][64];
  __shared__ __align__(16) u16 Vt[2][64][64];
  __shared__ __align__(16) u16 Ps[4][16][72];
  const int T = 2048, C = 1024;
  int tid = threadIdx.x;
  int wave = tid >> 6, lane = tid & 63;
  int quad = lane >> 4, l16 = lane & 15;
  int p = blockIdx.y;                       // 0..15 -> strips p and 31-p
  int bh = blockIdx.x;                      // 0..31 = b*16+h (fastest-varying)
  int b = bh >> 4, h = bh & 15;
  int wq[2];
  wq[0] = p * 64 + wave * 16;               // group A
  wq[1] = (31 - p) * 64 + wave * 16;        // group B
  int dt[2] = {p, 31 - p};                  // diagonal 64-key tile per group
  int nkt = 32 - p;                         // tiles 0..31-p

  bf16x8 bq[2][2];
#pragma unroll
  for (int g = 0; g < 2; ++g) {
    const u16* gq = q + (size_t)(b * T + wq[g] + l16) * C + h * 64 + quad * 8;
    bq[g][0] = __builtin_bit_cast(bf16x8, *(const ushortx8*)(gq));
    bq[g][1] = __builtin_bit_cast(bf16x8, *(const ushortx8*)(gq + 32));
  }

  ushortx8 onesu;
#pragma unroll
  for (int j = 0; j < 8; ++j) onesu[j] = 0x3F80;  // bf16 1.0
  bf16x8 bones = __builtin_bit_cast(bf16x8, onesu);

  // glds staging: issue (w + 4i) covers rows (w+4i)*8 .. +7; lane covers row +(lane>>3),
  // stored chunk (lane&7); global source column pre-swizzled by row&7 = lane>>3.
  int grow = lane >> 3;                     // row offset within 8-row group
  int gchk = ((lane & 7) ^ grow) * 8;       // pre-swizzled logical chunk
  const u16* kbase = k  + (size_t)(b * T + grow) * C + h * 64 + gchk;
  const u16* vbase = vt + (size_t)(bh * 64 + grow) * 2048 + gchk;

#define STAGE_KV(BB, KT)                                                                     \
  do {                                                                                       \
    _Pragma("unroll")                                                                        \
    for (int i_ = 0; i_ < 2; ++i_) {                                                         \
      int rb_ = (wave + 4 * i_) * 8;                                                         \
      GLDS16(kbase + (size_t)((KT) * 64 + rb_) * C, &Ks[BB][rb_][0]);                        \
      GLDS16(vbase + (size_t)rb_ * 2048 + (KT) * 64, &Vt[BB][rb_][0]);                       \
    }                                                                                        \
  } while (0)

  floatx4 o[2][5] = {};  // [group][0..3]=O tiles, [4]=row-sum l

  STAGE_KV(0, 0);
  __syncthreads();

  int rxk = l16 & 7;                        // row&7 for K/V frag reads

  for (int kt = 0; kt < nkt; ++kt) {
    int cur = kt & 1;
    if (kt + 1 < nkt) STAGE_KV(cur ^ 1, kt + 1);   // nb freed by the barrier ending kt-1

    bool act[2] = {kt <= dt[0], true};

    // S^T = K Q^T : lane holds S[q=l16][key = kt*64 + nt*16 + quad*4 + rg]
    floatx4 sacc[2][4] = {};
#pragma unroll
    for (int nt = 0; nt < 4; ++nt) {
      bf16x8 ak0 = __builtin_bit_cast(bf16x8, *(const ushortx8*)&Ks[cur][nt * 16 + l16][(quad ^ rxk) * 8]);
      bf16x8 ak1 = __builtin_bit_cast(bf16x8, *(const ushortx8*)&Ks[cur][nt * 16 + l16][((quad | 4) ^ rxk) * 8]);
#pragma unroll
      for (int g = 0; g < 2; ++g)
        if (act[g]) {
          sacc[g][nt] = __builtin_amdgcn_mfma_f32_16x16x32_bf16(ak0, bq[g][0], sacc[g][nt], 0, 0, 0);
          sacc[g][nt] = __builtin_amdgcn_mfma_f32_16x16x32_bf16(ak1, bq[g][1], sacc[g][nt], 0, 0, 0);
        }
    }

    // per group: mask+softmax, write shared Ps slot, read A-frag back (same-wave in-order DS)
    bf16x8 ap[2][2];
#pragma unroll
    for (int g = 0; g < 2; ++g)
      if (act[g]) {
        if (kt == dt[g]) {  // causal mask, this group's diagonal tile
          int qg = wq[g] + l16;
#pragma unroll
          for (int nt = 0; nt < 4; ++nt)
#pragma unroll
            for (int rg = 0; rg < 4; ++rg)
              if (kt * 64 + nt * 16 + quad * 4 + rg > qg) sacc[g][nt][rg] = -__builtin_inff();
        }
        // fixed m = 0: P = exp2(S), no running max / no rescale
#pragma unroll
        for (int nt = 0; nt < 4; ++nt) {
          float p0 = fexp2(sacc[g][nt][0]);
          float p1 = fexp2(sacc[g][nt][1]);
          float p2 = fexp2(sacc[g][nt][2]);
          float p3 = fexp2(sacc[g][nt][3]);
          unsigned lo = cvtpk(p0, p1);
          unsigned hi = cvtpk(p2, p3);
          *(uint2*)&Ps[wave][l16][nt * 16 + quad * 4] = make_uint2(lo, hi);
        }
        ap[g][0] = __builtin_bit_cast(bf16x8, *(const ushortx8*)&Ps[wave][l16][quad * 8]);
        ap[g][1] = __builtin_bit_cast(bf16x8, *(const ushortx8*)&Ps[wave][l16][32 + quad * 8]);
      }

#pragma unroll
    for (int nt = 0; nt < 4; ++nt) {
      bf16x8 bv0 = __builtin_bit_cast(bf16x8, *(const ushortx8*)&Vt[cur][nt * 16 + l16][(quad ^ rxk) * 8]);
      bf16x8 bv1 = __builtin_bit_cast(bf16x8, *(const ushortx8*)&Vt[cur][nt * 16 + l16][((quad | 4) ^ rxk) * 8]);
#pragma unroll
      for (int g = 0; g < 2; ++g)
        if (act[g]) {
          o[g][nt] = __builtin_amdgcn_mfma_f32_16x16x32_bf16(ap[g][0], bv0, o[g][nt], 0, 0, 0);
          o[g][nt] = __builtin_amdgcn_mfma_f32_16x16x32_bf16(ap[g][1], bv1, o[g][nt], 0, 0, 0);
        }
    }
#pragma unroll
    for (int g = 0; g < 2; ++g)
      if (act[g]) {
        o[g][4] = __builtin_amdgcn_mfma_f32_16x16x32_bf16(ap[g][0], bones, o[g][4], 0, 0, 0);
        o[g][4] = __builtin_amdgcn_mfma_f32_16x16x32_bf16(ap[g][1], bones, o[g][4], 0, 0, 0);
      }

    __syncthreads();  // single barrier per tile; drains glds (vmcnt) + LDS reads
  }
#undef STAGE_KV

#pragma unroll
  for (int g = 0; g < 2; ++g) {
    float inv[4];
#pragma unroll
    for (int rg = 0; rg < 4; ++rg) inv[rg] = __builtin_amdgcn_rcpf(o[g][4][rg]);
#pragma unroll
    for (int nt = 0; nt < 4; ++nt)
#pragma unroll
      for (int rg = 0; rg < 4; ++rg) {
        int qg = wq[g] + quad * 4 + rg;
        int col = h * 64 + nt * 16 + l16;
        y[(size_t)(b * T + qg) * C + col] = f2bf(o[g][nt][rg] * inv[rg]);
      }
  }
}

extern "C" void kernel_launch(void* const* d_in, const int* in_sizes, int n_in,
                              void* d_out, int out_size, void* d_ws, size_t ws_size,
                              hipStream_t stream) {
  const float* x  = (const float*)d_in[0];
  const float* Wq = (const float*)d_in[1];
  const float* Wk = (const float*)d_in[2];
  const float* Wv = (const float*)d_in[3];
  const float* Wo = (const float*)d_in[4];

  char* ws = (char*)d_ws;
  float* partials = (float*)ws;
  u16* Wt  = (u16*)(ws + 4096);                       // 4 x 1M bf16 ternary (Q,K,V,O stacked)
  u16* xb  = (u16*)(ws + 4096 + (size_t)(8u << 20));
  u16* qb  = xb + (4u << 20);                         // qb,kb contiguous (QKV epilogue routing)
  u16* kb  = qb + (4u << 20);
  u16* vtb = kb + (4u << 20);                         // V written directly transposed
  u16* yb  = vtb + (4u << 20);
  float* out = (float*)d_out;

  prep_kernel<<<2304, 256, 0, stream>>>(x, xb, Wq, Wk, Wv, Wo, partials);
  quant_kernel<<<dim3(512, 4), 256, 0, stream>>>(Wq, Wk, Wv, Wo, partials, Wt);

  gemm_qkv<<<dim3(32, 48), 256, 0, stream>>>(xb, Wt, qb, vtb, partials);  // RoPE + V-transpose fused
  attn_kernel<<<dim3(32, 16), 256, 0, stream>>>(qb, kb, vtb, yb);         // bh fastest -> per-XCD K/V L2 reuse
  gemm_out<<<dim3(32, 16), 256, 0, stream>>>(yb, Wt + 3 * (1u << 20), out, partials);
}